// Round 2
// baseline (10424.773 us; speedup 1.0000x reference)
//
#include <hip/hip_runtime.h>
#include <hip/hip_bf16.h>

// ---------------------------------------------------------------------------
// UnifiedModelRNN: B=256,S=512,I=64,H=256. Sequential scan, batch-parallel.
// 16 workgroups x 1024 threads (16 waves); wg g owns batch rows [16g,16g+16).
// ALL weights live in VGPRs (loaded once): gates Wc = 40 s16x8/lane (160 VGPR),
// head weights 8-32 VGPR by wave role. Gates GEMM = pure LDS-A + reg-B MFMA.
// A_lds double-buffered on t parity (5 barriers/step). Gates-h for t+1 is
// overlapped with the serial pit->time->ar head chain; only gates-x (8 MFMA)
// runs after x_{t+1} is produced.
// ---------------------------------------------------------------------------

typedef float f32x4 __attribute__((ext_vector_type(4)));
typedef short s16x8 __attribute__((ext_vector_type(8)));

#define S_LEN 512
#define I_DIM 64
#define H_DIM 256
#define K_DIM 320
#define BT    16
#define NT    1024

// ws element offsets (unsigned short = bf16 storage)
#define WS_WC    0        // Wc: 1024 x 320 row-major, [w_ih | w_hh]
#define WS_PW1   327680   // pit_w1: 64 x 256
#define WS_TW1   344064   // time_w1[:, :256]: 64 x 256
#define WS_ARW1X 360448   // ar_w1[:, 2:66]: 64 x 64
#define WS_ARW2  364544   // ar_w2: 64 x 64
#define WS_TOTAL 368640

#define OUT_PIT  0
#define OUT_TIME 131072
#define OUT_AR   262144

#define ALD 328   // [x_t|h] LDS row stride (bf16 elems)
#define XLD 72    // small 16x64 tiles row stride

__device__ __forceinline__ float sigf(float x) {
  return 1.0f / (1.0f + __expf(-x));
}
__device__ __forceinline__ float tanh_fast(float x) {
  float c = fminf(fmaxf(x, -15.0f), 15.0f);
  float e = __expf(2.0f * c);
  return (e - 1.0f) / (e + 1.0f);
}
__device__ __forceinline__ unsigned short f2bf(float f) {
  __hip_bfloat16 h = __float2bfloat16(f);
  return *reinterpret_cast<unsigned short*>(&h);
}

__global__ void prep_kernel(const float* __restrict__ w_ih,
                            const float* __restrict__ w_hh,
                            const float* __restrict__ pit_w1,
                            const float* __restrict__ time_w1,
                            const float* __restrict__ ar_w1,
                            const float* __restrict__ ar_w2,
                            unsigned short* __restrict__ ws) {
  int idx = blockIdx.x * 256 + threadIdx.x;
  if (idx >= WS_TOTAL) return;
  float v;
  if (idx < WS_PW1) {
    int r = idx / K_DIM;
    int k = idx - r * K_DIM;
    v = (k < I_DIM) ? w_ih[r * I_DIM + k] : w_hh[r * H_DIM + (k - I_DIM)];
  } else if (idx < WS_TW1) {
    v = pit_w1[idx - WS_PW1];
  } else if (idx < WS_ARW1X) {
    int e = idx - WS_TW1;
    int j = e >> 8, k = e & 255;
    v = time_w1[j * 257 + k];
  } else if (idx < WS_ARW2) {
    int e = idx - WS_ARW1X;
    int j = e >> 6, k = e & 63;
    v = ar_w1[j * 66 + 2 + k];
  } else {
    v = ar_w2[idx - WS_ARW2];
  }
  ws[idx] = f2bf(v);
}

__global__ __launch_bounds__(NT) void rnn_kernel(
    const float* __restrict__ x,
    const float* __restrict__ b_ih, const float* __restrict__ b_hh,
    const float* __restrict__ pit_b1, const float* __restrict__ pit_w2,
    const float* __restrict__ pit_b2,
    const float* __restrict__ time_w1, const float* __restrict__ time_b1,
    const float* __restrict__ time_w2, const float* __restrict__ time_b2,
    const float* __restrict__ ar_w1, const float* __restrict__ ar_b1,
    const float* __restrict__ ar_b2,
    const unsigned short* __restrict__ ws,
    float* __restrict__ out)
{
  __shared__ __align__(16) unsigned short A_lds[2][16][ALD];  // [x(64)|h(256)] bf16, t-parity dbuf
  __shared__ __align__(16) unsigned short xo_lds[16][XLD];    // x_orig[t] bf16
  __shared__ __align__(16) unsigned short ar1_lds[16][XLD];   // relu(ar1) bf16
  __shared__ float pitp[4][16];
  __shared__ float timep[4][16];

  const int tid  = threadIdx.x;
  const int wave = tid >> 6;
  const int lane = tid & 63;
  const int lrow = lane & 15;   // MFMA: A-row / B-col / D-col
  const int lgrp = lane >> 4;   // MFMA: k-group / D-row-group
  const int b0   = blockIdx.x * BT;
  const int hc   = (wave & 3) * 16 + lrow;  // head col 0..63 within role group

  // ---- zero both A buffers ----
  for (int i = tid; i < 2 * 16 * ALD; i += NT) (&A_lds[0][0][0])[i] = 0;

  const int srow = tid >> 6;   // staging row = wave
  const int scol = tid & 63;   // staging col
  const size_t xbase = (size_t)(b0 + srow) * S_LEN * I_DIM + scol;
  float xpre = x[xbase];  // x[:,0,:]
  __syncthreads();
  A_lds[0][srow][scol] = f2bf(xpre);
  out[OUT_AR + xbase] = xpre;  // ar_out[:,0,:] = x[:,0,:]

  // ---- register-resident weights ----
  s16x8 wg[4][10];  // gates: wave owns hidden [16w,16w+16), 4 gate quadrants
#pragma unroll
  for (int q = 0; q < 4; ++q)
#pragma unroll
    for (int kt = 0; kt < 10; ++kt)
      wg[q][kt] = *reinterpret_cast<const s16x8*>(
          &ws[WS_WC + (q * 256 + wave * 16 + lrow) * K_DIM + kt * 32 + 8 * lgrp]);

  float bias_q[4];
#pragma unroll
  for (int q = 0; q < 4; ++q) {
    int g = q * 256 + wave * 16 + lrow;
    bias_q[q] = b_ih[g] + b_hh[g];
  }

  s16x8 hw1[8];  // waves 0-3: pit_w1 ; waves 4-7: time_w1[:, :256]
  s16x8 arw[2];  // waves 8-11: ar_w1[:,2:66] ; waves 12-15: ar_w2
  float hb1 = 0, hw2 = 0, hwlast = 0, harp = 0, hart = 0, harb1 = 0, harb2 = 0;
  if (wave < 4) {
#pragma unroll
    for (int kt = 0; kt < 8; ++kt)
      hw1[kt] = *reinterpret_cast<const s16x8*>(
          &ws[WS_PW1 + hc * 256 + kt * 32 + 8 * lgrp]);
    hb1 = pit_b1[hc];
    hw2 = pit_w2[hc];
  } else if (wave < 8) {
#pragma unroll
    for (int kt = 0; kt < 8; ++kt)
      hw1[kt] = *reinterpret_cast<const s16x8*>(
          &ws[WS_TW1 + hc * 256 + kt * 32 + 8 * lgrp]);
    hb1    = time_b1[hc];
    hw2    = time_w2[hc];
    hwlast = time_w1[hc * 257 + 256];
  } else if (wave < 12) {
#pragma unroll
    for (int kt = 0; kt < 2; ++kt)
      arw[kt] = *reinterpret_cast<const s16x8*>(
          &ws[WS_ARW1X + hc * 64 + kt * 32 + 8 * lgrp]);
    harb1 = ar_b1[hc];
    harp  = ar_w1[hc * 66 + 0];
    hart  = ar_w1[hc * 66 + 1];
  } else {
#pragma unroll
    for (int kt = 0; kt < 2; ++kt)
      arw[kt] = *reinterpret_cast<const s16x8*>(
          &ws[WS_ARW2 + hc * 64 + kt * 32 + 8 * lgrp]);
    harb2 = ar_b2[hc];
  }
  const float pb2 = pit_b2[0], tb2 = time_b2[0];

  float cst[4] = {0.0f, 0.0f, 0.0f, 0.0f};

  __syncthreads();

  // ---- prologue: full gates(0) from A_lds[0] ----
  f32x4 acc[4];
  {
    s16x8 a0[10];
#pragma unroll
    for (int kt = 0; kt < 10; ++kt)
      a0[kt] = *reinterpret_cast<const s16x8*>(&A_lds[0][lrow][kt * 32 + 8 * lgrp]);
#pragma unroll
    for (int q = 0; q < 4; ++q) {
      f32x4 tv; tv[0] = tv[1] = tv[2] = tv[3] = bias_q[q];
      acc[q] = tv;
    }
#pragma unroll
    for (int kt = 0; kt < 10; ++kt)
#pragma unroll
      for (int q = 0; q < 4; ++q)
        acc[q] = __builtin_amdgcn_mfma_f32_16x16x32_bf16(a0[kt], wg[q][kt], acc[q], 0, 0, 0);
  }

  // =========================== time loop ===========================
  for (int t = 0; t < S_LEN; ++t) {
    const int nb = (t + 1) & 1;  // buffer receiving h_new / x_{t+1}

    // stage x_orig[t] (read by waves 8-11 after sync_a), prefetch x[t+1]
    xo_lds[srow][scol] = f2bf(xpre);
    if (t + 1 < S_LEN) xpre = x[xbase + (size_t)(t + 1) * I_DIM];

    // ---- LSTM update (c in regs), h -> A_lds[nb] ----
#pragma unroll
    for (int r = 0; r < 4; ++r) {
      float ig = sigf(acc[0][r]);
      float fg = sigf(acc[1][r]);
      float gg = tanh_fast(acc[2][r]);
      float og = sigf(acc[3][r]);
      float c  = fg * cst[r] + ig * gg;
      cst[r] = c;
      A_lds[nb][lgrp * 4 + r][64 + wave * 16 + lrow] = f2bf(og * tanh_fast(c));
    }
    __syncthreads();  // sync_a: h + xo ready

    // shared h fragments (feed heads AND gates-h)
    s16x8 hfr[8];
#pragma unroll
    for (int kt = 0; kt < 8; ++kt)
      hfr[kt] = *reinterpret_cast<const s16x8*>(&A_lds[nb][lrow][64 + kt * 32 + 8 * lgrp]);

    // ---- P1 head MFMAs (latency-critical) ----
    f32x4 hacc, aracc;
    if (wave < 8) {
      hacc[0] = hacc[1] = hacc[2] = hacc[3] = hb1;
#pragma unroll
      for (int kt = 0; kt < 8; ++kt)
        hacc = __builtin_amdgcn_mfma_f32_16x16x32_bf16(hfr[kt], hw1[kt], hacc, 0, 0, 0);
    } else if (wave < 12) {
      aracc[0] = aracc[1] = aracc[2] = aracc[3] = harb1;
#pragma unroll
      for (int kt = 0; kt < 2; ++kt) {
        s16x8 xa = *reinterpret_cast<const s16x8*>(&xo_lds[lrow][kt * 32 + 8 * lgrp]);
        aracc = __builtin_amdgcn_mfma_f32_16x16x32_bf16(xa, arw[kt], aracc, 0, 0, 0);
      }
    }

    // ---- gates-h for t+1 (32 MFMA, drains behind the head chain) ----
    f32x4 acc2[4];
#pragma unroll
    for (int q = 0; q < 4; ++q) {
      f32x4 tv; tv[0] = tv[1] = tv[2] = tv[3] = bias_q[q];
      acc2[q] = tv;
    }
#pragma unroll
    for (int kt = 0; kt < 8; ++kt)
#pragma unroll
      for (int q = 0; q < 4; ++q)
        acc2[q] = __builtin_amdgcn_mfma_f32_16x16x32_bf16(hfr[kt], wg[q][kt + 2], acc2[q], 0, 0, 0);

    // pit reduction
    if (wave < 4) {
      float v[4];
#pragma unroll
      for (int r = 0; r < 4; ++r) v[r] = fmaxf(hacc[r], 0.0f) * hw2;
#pragma unroll
      for (int off = 1; off < 16; off <<= 1)
#pragma unroll
        for (int r = 0; r < 4; ++r) v[r] += __shfl_xor(v[r], off);
      if (lrow == 0) {
#pragma unroll
        for (int r = 0; r < 4; ++r) pitp[wave][lgrp * 4 + r] = v[r];
      }
    }
    __syncthreads();  // sync_c: pit partials ready

    // ---- P2: time finish (waves 4-7); pit out (wave 0) ----
    if (wave >= 4 && wave < 8) {
      float v[4];
#pragma unroll
      for (int r = 0; r < 4; ++r) {
        int row = lgrp * 4 + r;
        float pv = pitp[0][row] + pitp[1][row] + pitp[2][row] + pitp[3][row] + pb2;
        v[r] = fmaxf(hacc[r] + pv * hwlast, 0.0f) * hw2;
      }
#pragma unroll
      for (int off = 1; off < 16; off <<= 1)
#pragma unroll
        for (int r = 0; r < 4; ++r) v[r] += __shfl_xor(v[r], off);
      if (lrow == 0) {
#pragma unroll
        for (int r = 0; r < 4; ++r) timep[wave - 4][lgrp * 4 + r] = v[r];
      }
    } else if (wave == 0 && lane < 16) {
      float pv = pitp[0][lane] + pitp[1][lane] + pitp[2][lane] + pitp[3][lane] + pb2;
      out[OUT_PIT + (size_t)(b0 + lane) * S_LEN + t] = pv;
    }
    __syncthreads();  // sync_d: time partials ready

    // ---- P3: ar1 finish (waves 8-11); time out (wave 4) ----
    if (wave >= 8 && wave < 12) {
#pragma unroll
      for (int r = 0; r < 4; ++r) {
        int row = lgrp * 4 + r;
        float pv = pitp[0][row] + pitp[1][row] + pitp[2][row] + pitp[3][row] + pb2;
        float tv = timep[0][row] + timep[1][row] + timep[2][row] + timep[3][row] + tb2;
        float a1 = aracc[r] + pv * harp + tv * hart;
        ar1_lds[row][hc] = f2bf(fmaxf(a1, 0.0f));
      }
    } else if (wave == 4 && lane < 16) {
      float tv = timep[0][lane] + timep[1][lane] + timep[2][lane] + timep[3][lane] + tb2;
      out[OUT_TIME + (size_t)(b0 + lane) * S_LEN + t] = tv;
    }
    __syncthreads();  // sync_e: ar1 ready

    // ---- P4: ar2 -> nxt (waves 12-15); write ar_out[t+1] + x_{t+1} ----
    if (wave >= 12) {
      f32x4 nacc;
      nacc[0] = nacc[1] = nacc[2] = nacc[3] = harb2;
#pragma unroll
      for (int kt = 0; kt < 2; ++kt) {
        s16x8 af = *reinterpret_cast<const s16x8*>(&ar1_lds[lrow][kt * 32 + 8 * lgrp]);
        nacc = __builtin_amdgcn_mfma_f32_16x16x32_bf16(af, arw[kt], nacc, 0, 0, 0);
      }
#pragma unroll
      for (int r = 0; r < 4; ++r) {
        int row = lgrp * 4 + r;
        float nv = nacc[r];
        if (t < S_LEN - 1)
          out[OUT_AR + (size_t)(b0 + row) * S_LEN * I_DIM + (size_t)(t + 1) * I_DIM + hc] = nv;
        A_lds[nb][row][hc] = f2bf(nv);
      }
    }
    __syncthreads();  // sync_f: x_{t+1} staged

    // ---- gates-x for t+1 (8 MFMA) -> commit acc ----
#pragma unroll
    for (int kt = 0; kt < 2; ++kt) {
      s16x8 xa = *reinterpret_cast<const s16x8*>(&A_lds[nb][lrow][kt * 32 + 8 * lgrp]);
#pragma unroll
      for (int q = 0; q < 4; ++q)
        acc2[q] = __builtin_amdgcn_mfma_f32_16x16x32_bf16(xa, wg[q][kt], acc2[q], 0, 0, 0);
    }
#pragma unroll
    for (int q = 0; q < 4; ++q) acc[q] = acc2[q];
  }
}

extern "C" void kernel_launch(void* const* d_in, const int* in_sizes, int n_in,
                              void* d_out, int out_size, void* d_ws, size_t ws_size,
                              hipStream_t stream) {
  const float* x       = (const float*)d_in[0];
  const float* w_ih    = (const float*)d_in[1];
  const float* w_hh    = (const float*)d_in[2];
  const float* b_ih    = (const float*)d_in[3];
  const float* b_hh    = (const float*)d_in[4];
  const float* pit_w1  = (const float*)d_in[5];
  const float* pit_b1  = (const float*)d_in[6];
  const float* pit_w2  = (const float*)d_in[7];
  const float* pit_b2  = (const float*)d_in[8];
  const float* time_w1 = (const float*)d_in[9];
  const float* time_b1 = (const float*)d_in[10];
  const float* time_w2 = (const float*)d_in[11];
  const float* time_b2 = (const float*)d_in[12];
  const float* ar_w1   = (const float*)d_in[13];
  const float* ar_b1   = (const float*)d_in[14];
  const float* ar_w2   = (const float*)d_in[15];
  const float* ar_b2   = (const float*)d_in[16];
  unsigned short* ws   = (unsigned short*)d_ws;
  float* out           = (float*)d_out;

  prep_kernel<<<dim3((WS_TOTAL + 255) / 256), dim3(256), 0, stream>>>(
      w_ih, w_hh, pit_w1, time_w1, ar_w1, ar_w2, ws);
  rnn_kernel<<<dim3(16), dim3(NT), 0, stream>>>(
      x, b_ih, b_hh, pit_b1, pit_w2, pit_b2,
      time_w1, time_b1, time_w2, time_b2,
      ar_w1, ar_b1, ar_b2, ws, out);
}